// Round 12
// baseline (87.541 us; speedup 1.0000x reference)
//
#include <hip/hip_runtime.h>

// Radon3D loss on MI355X — project the DIFFERENCE volume (radon is linear).
// Geometry (D=H=W=64, 120 angles over [0,120] deg): L=91, pad top=left=13.
//   ix(i,j) = 45*c*linj + 32 + 45*s - s*i,  iy(i,j) = 45*s*linj + 32 - 45*c + c*i
// Effective-clock model (R2..R11): device runs these kernels at ~1.2 GHz;
// minimize max(LDS cyc/CU, VALU cyc/SIMD) with >=3 waves/SIMD, >=240 blocks.
// This round: fp8 8-slice WIDE cells (16 B = [P8(y,x) | P8(y,x+1)]) -> 2 x
// ds_read_b128/iter for EIGHT slices (LDS/CU halves vs R7) + i-half split
// across block pairs (480 blocks x 6 waves = 2 blocks/CU = 12 waves/CU).
// Partial column sums -> d_ws; finalize applies abs AFTER the full i-sum.
// Coords shifted +1 (nonneg), clamped to [0,65]: out-of-support samples hit
// the zero border with zero weight == map_coordinates mode='constant' cval=0.
#define DD 64
#define NA 120
#define LL 91
#define PS 67
#define PSTR 69
#define NCELL (PS * PSTR)       // 4623 cells * 16 B = 74.0 KB
#define NSL 8                   // slices per block (fp8 byte-lanes)
#define NANG 4                  // angles per block
#define JT 96                   // j-lanes per angle (91 active)
#define NTHR (NANG * JT)        // 384 threads = 6 waves
#define NGRP (64 / NSL)         // 8 slice groups
#define NAP (NA / NANG)         // 30 angle groups
#define NHALF (NGRP * NAP)      // 240 blocks per i-half
#define NBLKS (2 * NHALF)       // 480 -> 2 blocks/CU, balanced
#define IH_SPLIT 46             // half 0: [0,46), half 1: [46,91)

typedef float f32x2 __attribute__((ext_vector_type(2)));

static __device__ __forceinline__ void pk_acc(f32x2& acc, float w, f32x2 v) {
    acc.x = fmaf(w, v.x, acc.x);
    acc.y = fmaf(w, v.y, acc.y);
}

__global__ __launch_bounds__(NTHR, 3) void radon_half_kernel(
    const float* __restrict__ vout, const float* __restrict__ vgt,
    float4* __restrict__ part)
{
    __shared__ uint4 C[NCELL];          // wide fp8 canvas, 74 KB

    const int bid = blockIdx.x;
    const int h   = bid / NHALF;        // i-half 0/1
    const int rem = bid - h * NHALF;
    const int g   = rem / NAP;          // slice group 0..7
    const int ap  = rem - g * NAP;      // angle group 0..29
    const int s0  = g * NSL;
    const int t   = threadIdx.x;

    // 1) zero the padded wide canvas
    for (int idx = t; idx < NCELL; idx += NTHR)
        C[idx] = make_uint4(0u, 0u, 0u, 0u);
    __syncthreads();

    // 2) stage fp8 diffs of 8 slices. Pixel (d,w) -> 8 B pack, written to
    //    cell(d+1, w+1) dwords 0,1 ("x") and cell(d+1, w) dwords 2,3 ("x+1").
    for (int idx = t; idx < DD * DD; idx += NTHR) {
        const int d = idx >> 6, w = idx & 63;
        const int gb = d * 4096 + s0 * 64 + w;
        float df[NSL];
        #pragma unroll
        for (int k = 0; k < NSL; ++k)
            df[k] = vout[gb + 64 * k] - vgt[gb + 64 * k];
        int p0 = 0, p1 = 0;
        p0 = __builtin_amdgcn_cvt_pk_fp8_f32(df[0], df[1], p0, false);
        p0 = __builtin_amdgcn_cvt_pk_fp8_f32(df[2], df[3], p0, true);
        p1 = __builtin_amdgcn_cvt_pk_fp8_f32(df[4], df[5], p1, false);
        p1 = __builtin_amdgcn_cvt_pk_fp8_f32(df[6], df[7], p1, true);
        const int rb = (d + 1) * PSTR + w;
        ((uint2*)&C[rb + 1])[0] = make_uint2((unsigned)p0, (unsigned)p1);
        ((uint2*)&C[rb])[1]     = make_uint2((unsigned)p0, (unsigned)p1);
    }
    __syncthreads();

    // 3) projection over this block's i-half: thread = (angle slot, column j)
    const int ja = t / JT;
    const int j  = t - ja * JT;
    const int a  = ap * NANG + ja;
    const float theta = (float)a * (float)(3.14159265358979323846 * 120.0 / 119.0 / 180.0);
    const float c = cosf(theta), sn = sinf(theta);

    if (j < JT) {
        const float linj = fmaf((float)j, 2.0f / 90.0f, -1.0f);
        // +1 shift: coords in [0,65] after clamp; canvas row/col 0 is border
        const float bx1 = fmaf(c,  linj, 1.0f) * 45.0f - 12.0f + 45.0f * sn;
        const float by1 = fmaf(sn, linj, 1.0f) * 45.0f - 12.0f - 45.0f * c;
        const int i0 = h ? IH_SPLIT : 0;
        const int i1 = h ? LL : IH_SPLIT;
        f32x2 acc0 = {0.f, 0.f}, acc1 = {0.f, 0.f};
        f32x2 acc2 = {0.f, 0.f}, acc3 = {0.f, 0.f};
        #pragma unroll 3
        for (int i = i0; i < i1; ++i) {
            const float xs = fminf(fmaxf(fmaf(-(float)i, sn, bx1), 0.0f), 65.0f);
            const float ys = fminf(fmaxf(fmaf( (float)i, c,  by1), 0.0f), 65.0f);
            const int ix = (int)xs;          // trunc == floor (nonneg)
            const int iy = (int)ys;
            const float wx = xs - (float)ix;
            const float wy = ys - (float)iy;
            const float ux = 1.f - wx, uy = 1.f - wy;
            const float w00 = ux * uy, w01 = wx * uy;
            const float w10 = ux * wy, w11 = wx * wy;
            const int ci = iy * PSTR + ix;
            const uint4 q0 = C[ci];          // row y  : [P8(x) | P8(x+1)]
            const uint4 q1 = C[ci + PSTR];   // row y+1: [P8(x) | P8(x+1)]
            pk_acc(acc0, w00, __builtin_amdgcn_cvt_pk_f32_fp8(q0.x, false));
            pk_acc(acc1, w00, __builtin_amdgcn_cvt_pk_f32_fp8(q0.x, true));
            pk_acc(acc2, w00, __builtin_amdgcn_cvt_pk_f32_fp8(q0.y, false));
            pk_acc(acc3, w00, __builtin_amdgcn_cvt_pk_f32_fp8(q0.y, true));
            pk_acc(acc0, w01, __builtin_amdgcn_cvt_pk_f32_fp8(q0.z, false));
            pk_acc(acc1, w01, __builtin_amdgcn_cvt_pk_f32_fp8(q0.z, true));
            pk_acc(acc2, w01, __builtin_amdgcn_cvt_pk_f32_fp8(q0.w, false));
            pk_acc(acc3, w01, __builtin_amdgcn_cvt_pk_f32_fp8(q0.w, true));
            pk_acc(acc0, w10, __builtin_amdgcn_cvt_pk_f32_fp8(q1.x, false));
            pk_acc(acc1, w10, __builtin_amdgcn_cvt_pk_f32_fp8(q1.x, true));
            pk_acc(acc2, w10, __builtin_amdgcn_cvt_pk_f32_fp8(q1.y, false));
            pk_acc(acc3, w10, __builtin_amdgcn_cvt_pk_f32_fp8(q1.y, true));
            pk_acc(acc0, w11, __builtin_amdgcn_cvt_pk_f32_fp8(q1.z, false));
            pk_acc(acc1, w11, __builtin_amdgcn_cvt_pk_f32_fp8(q1.z, true));
            pk_acc(acc2, w11, __builtin_amdgcn_cvt_pk_f32_fp8(q1.w, false));
            pk_acc(acc3, w11, __builtin_amdgcn_cvt_pk_f32_fp8(q1.w, true));
        }
        // partial (pre-abs) column sums for this i-half -> d_ws
        const long pi = (long)(((h * NGRP + g) * NA + a) * JT + j) * 2;
        part[pi]     = make_float4(acc0.x, acc0.y, acc1.x, acc1.y);
        part[pi + 1] = make_float4(acc2.x, acc2.y, acc3.x, acc3.y);
    }
}

#define PHALF (NGRP * NA * JT * 2)      // float4 entries per half
#define NENT (NGRP * NA * LL)           // 87360 finalize entries

__global__ __launch_bounds__(256) void finalize_kernel(
    const float4* __restrict__ part, float* __restrict__ out)
{
    __shared__ float wsum[4];
    float v = 0.f;
    for (int e = blockIdx.x * 256 + threadIdx.x; e < NENT; e += gridDim.x * 256) {
        const int ga = e / LL;            // g*NA + a
        const int j  = e - ga * LL;
        const int pi = (ga * JT + j) * 2;
        const float4 a0 = part[pi],         a1 = part[pi + 1];
        const float4 b0 = part[PHALF + pi], b1 = part[PHALF + pi + 1];
        v += fabsf(a0.x + b0.x) + fabsf(a0.y + b0.y)
           + fabsf(a0.z + b0.z) + fabsf(a0.w + b0.w)
           + fabsf(a1.x + b1.x) + fabsf(a1.y + b1.y)
           + fabsf(a1.z + b1.z) + fabsf(a1.w + b1.w);
    }
    #pragma unroll
    for (int off = 32; off > 0; off >>= 1)
        v += __shfl_down(v, off);
    const int wave = threadIdx.x >> 6, lane = threadIdx.x & 63;
    if (lane == 0) wsum[wave] = v;
    __syncthreads();
    if (threadIdx.x == 0) {
        const float s = wsum[0] + wsum[1] + wsum[2] + wsum[3];
        atomicAdd(out, s * (1.0f / (float)(NA * LL)));
    }
}

extern "C" void kernel_launch(void* const* d_in, const int* in_sizes, int n_in,
                              void* d_out, int out_size, void* d_ws, size_t ws_size,
                              hipStream_t stream) {
    const float* vout = (const float*)d_in[0];
    const float* vgt  = (const float*)d_in[1];
    float* out = (float*)d_out;
    float4* part = (float4*)d_ws;    // 2 * 8*120*96*2 float4 = 5.9 MB

    hipMemsetAsync(out, 0, sizeof(float), stream);
    radon_half_kernel<<<NBLKS, NTHR, 0, stream>>>(vout, vgt, part);
    finalize_kernel<<<256, 256, 0, stream>>>(part, out);
}